// Round 3
// baseline (157.220 us; speedup 1.0000x reference)
//
#include <hip/hip_runtime.h>

// GruDirection2d forward_h: h[t] = z[t]*h_tilde[t] + (1-z[t])*h[t-1], scan over H.
// Shapes: z, h_tilde [B=4, C=64, H=512, W=512] f32; h0 [B, C, 1, W] f32.
// One thread per (b,c,w) chain. H processed in 64 stages of U=8 rows with
// EXPLICIT register double-buffering (A/B arrays, static indices): stage k+1's
// 16 loads are issued before stage k's compute+store, so each wave keeps ~4KB
// of loads in flight and the kernel is HBM-throughput-bound instead of
// latency-bound (R1 was ~700 cy stall per iteration: stores between loads
// blocked load hoisting).

constexpr int Bc = 4;
constexpr int Cc = 64;
constexpr int Hc = 512;
constexpr int Wc = 512;
constexpr int U  = 8;          // rows per pipeline stage
constexpr int NB = Hc / U;     // 64 stages

__global__ __launch_bounds__(256) void gru_h_scan(const float* __restrict__ z,
                                                  const float* __restrict__ ht,
                                                  const float* __restrict__ h0,
                                                  float* __restrict__ out) {
    const int cid = blockIdx.x * blockDim.x + threadIdx.x;  // [0, B*C*W)
    const int bc = cid >> 9;          // / Wc
    const int w  = cid & (Wc - 1);

    const size_t base = (size_t)bc * Hc * Wc + w;
    const float* zp = z + base;
    const float* hp = ht + base;
    float*       op = out + base;

    float h = h0[(size_t)bc * Wc + w];

    float zA[U], cA[U], zB[U], cB[U];

    // Prologue: stage 0 -> A
#pragma unroll
    for (int i = 0; i < U; ++i) {
        zA[i] = zp[(size_t)i * Wc];
        cA[i] = hp[(size_t)i * Wc];
    }

    for (int b = 0; b < NB; b += 2) {
        const size_t rowB = (size_t)(b + 1) * U * Wc;
        // Issue loads for stage b+1 -> B (independent of h-chain)
#pragma unroll
        for (int i = 0; i < U; ++i) {
            zB[i] = zp[rowB + (size_t)i * Wc];
            cB[i] = hp[rowB + (size_t)i * Wc];
        }
        // Compute + store stage b from A
        const size_t rowA = (size_t)b * U * Wc;
#pragma unroll
        for (int i = 0; i < U; ++i) {
            h = fmaf(zA[i], cA[i], (1.0f - zA[i]) * h);
            op[rowA + (size_t)i * Wc] = h;
        }
        // Issue loads for stage b+2 -> A
        if (b + 2 < NB) {
            const size_t rowA2 = (size_t)(b + 2) * U * Wc;
#pragma unroll
            for (int i = 0; i < U; ++i) {
                zA[i] = zp[rowA2 + (size_t)i * Wc];
                cA[i] = hp[rowA2 + (size_t)i * Wc];
            }
        }
        // Compute + store stage b+1 from B
#pragma unroll
        for (int i = 0; i < U; ++i) {
            h = fmaf(zB[i], cB[i], (1.0f - zB[i]) * h);
            op[rowB + (size_t)i * Wc] = h;
        }
    }
}

extern "C" void kernel_launch(void* const* d_in, const int* in_sizes, int n_in,
                              void* d_out, int out_size, void* d_ws, size_t ws_size,
                              hipStream_t stream) {
    const float* z = (const float*)d_in[0];
    const float* h_tilde = (const float*)d_in[1];
    const float* h0 = (const float*)d_in[2];
    float* out = (float*)d_out;

    const int n_chains = Bc * Cc * Wc;      // 131072 scalar chains
    const int block = 256;
    const int grid = n_chains / block;      // 512 blocks -> 8 waves/CU
    gru_h_scan<<<grid, block, 0, stream>>>(z, h_tilde, h0, out);
}

// Round 4
// 155.800 us; speedup vs baseline: 1.0091x; 1.0091x over previous
//
#include <hip/hip_runtime.h>

// GruDirection2d forward_h: h[t] = z[t]*h_tilde[t] + (1-z[t])*h[t-1], scan over H.
// Shapes: z, h_tilde [B=4, C=64, H=512, W=512] f32; h0 [B, C, 1, W] f32.
//
// R2 post-mortem: source-level double-buffering was DELETED by the compiler
// (VGPR_Count=28 proves <=2 loads in flight; measured 2.8 TB/s matches
// Little's law for that depth). Fix: __builtin_amdgcn_sched_barrier(0)
// fences pin the load blocks so the machine scheduler cannot sink the
// prefetch loads into the consume stage, and __launch_bounds__(256,2)
// raises the VGPR cap to 128 so 16 in-flight loads are allocatable.

constexpr int Bc = 4;
constexpr int Cc = 64;
constexpr int Hc = 512;
constexpr int Wc = 512;
constexpr int U  = 8;          // rows per pipeline stage
constexpr int NB = Hc / U;     // 64 stages

#define SCHED_FENCE() __builtin_amdgcn_sched_barrier(0)

__global__ __launch_bounds__(256, 2) void gru_h_scan(const float* __restrict__ z,
                                                     const float* __restrict__ ht,
                                                     const float* __restrict__ h0,
                                                     float* __restrict__ out) {
    const int cid = blockIdx.x * blockDim.x + threadIdx.x;  // [0, B*C*W)
    const int bc = cid >> 9;          // / Wc
    const int w  = cid & (Wc - 1);

    const size_t base = (size_t)bc * Hc * Wc + w;
    const float* zp = z + base;
    const float* hp = ht + base;
    float*       op = out + base;

    float h = h0[(size_t)bc * Wc + w];

    float zA[U], cA[U], zB[U], cB[U];

    // Prologue: stage 0 -> A
#pragma unroll
    for (int i = 0; i < U; ++i) {
        zA[i] = zp[(size_t)i * Wc];
        cA[i] = hp[(size_t)i * Wc];
    }

    for (int b = 0; b < NB; b += 2) {
        const size_t rowB = (size_t)(b + 1) * U * Wc;
        // --- issue stage b+1 loads -> B (must stay ABOVE stage-b compute) ---
        SCHED_FENCE();
#pragma unroll
        for (int i = 0; i < U; ++i) {
            zB[i] = zp[rowB + (size_t)i * Wc];
            cB[i] = hp[rowB + (size_t)i * Wc];
        }
        SCHED_FENCE();
        // --- compute + store stage b from A (waitcnt for B lands after) ---
        const size_t rowA = (size_t)b * U * Wc;
#pragma unroll
        for (int i = 0; i < U; ++i) {
            h = fmaf(zA[i], cA[i], (1.0f - zA[i]) * h);
            op[rowA + (size_t)i * Wc] = h;
        }
        SCHED_FENCE();
        // --- issue stage b+2 loads -> A ---
        if (b + 2 < NB) {
            const size_t rowA2 = (size_t)(b + 2) * U * Wc;
#pragma unroll
            for (int i = 0; i < U; ++i) {
                zA[i] = zp[rowA2 + (size_t)i * Wc];
                cA[i] = hp[rowA2 + (size_t)i * Wc];
            }
        }
        SCHED_FENCE();
        // --- compute + store stage b+1 from B ---
#pragma unroll
        for (int i = 0; i < U; ++i) {
            h = fmaf(zB[i], cB[i], (1.0f - zB[i]) * h);
            op[rowB + (size_t)i * Wc] = h;
        }
    }
}

extern "C" void kernel_launch(void* const* d_in, const int* in_sizes, int n_in,
                              void* d_out, int out_size, void* d_ws, size_t ws_size,
                              hipStream_t stream) {
    const float* z = (const float*)d_in[0];
    const float* h_tilde = (const float*)d_in[1];
    const float* h0 = (const float*)d_in[2];
    float* out = (float*)d_out;

    const int n_chains = Bc * Cc * Wc;      // 131072 scalar chains
    const int block = 256;
    const int grid = n_chains / block;      // 512 blocks -> 8 waves/CU
    gru_h_scan<<<grid, block, 0, stream>>>(z, h_tilde, h0, out);
}